// Round 2
// 130.249 us; speedup vs baseline: 1.0195x; 1.0195x over previous
//
#include <hip/hip_runtime.h>
#include <math.h>

#define Bb 8
#define Tt 2048
#define Cc 1024
#define Hh 64
#define BT (Bb * Tt)          // 16384 tokens
#define SLOG2E 0.18033688011112042f   // 0.125 * log2(e)

typedef __attribute__((ext_vector_type(8))) short short8;
typedef __attribute__((ext_vector_type(4))) short s16x4;
typedef __attribute__((ext_vector_type(4))) float floatx4;
typedef __attribute__((ext_vector_type(4))) unsigned int uint4v;

__device__ inline unsigned short f2bf(float f) {
  unsigned int u = __builtin_bit_cast(unsigned int, f);
  u += 0x7fff + ((u >> 16) & 1);   // RNE
  return (unsigned short)(u >> 16);
}
__device__ inline float bf2f(unsigned short u) {
  unsigned int x = ((unsigned int)u) << 16;
  return __builtin_bit_cast(float, x);
}

// ---------- Kernel 0: W fp32 [C][H] -> WTf bf16 fragment-major ----------
// WTf element (n in 0..191, k in 0..1023) at
//   ((g*32 + kc)*64 + quad*16 + lrow)*8 + j
__global__ __launch_bounds__(256) void wconv2(
    const float* __restrict__ Wq, const float* __restrict__ Wk,
    const float* __restrict__ Wv, unsigned short* __restrict__ WTf) {
  int bid = blockIdx.x;
  int w = bid >> 5;            // which W
  int kc = bid & 31;           // 32-k chunk
  const float* __restrict__ W = (w == 0) ? Wq : (w == 1 ? Wk : Wv);
  int t = threadIdx.x;
  int hg = t >> 6, quad = (t >> 4) & 3, lrow = t & 15;
  int g = w * 4 + hg;
  int h = hg * 16 + lrow;
  unsigned short tmp[8];
#pragma unroll
  for (int j = 0; j < 8; ++j)
    tmp[j] = f2bf(W[(size_t)(kc * 32 + quad * 8 + j) * Hh + h]);
  unsigned short* dst = &WTf[((size_t)(g * 32 + kc) * 64 + quad * 16 + lrow) * 8];
  *(ushort4*)dst = make_ushort4(tmp[0], tmp[1], tmp[2], tmp[3]);
  *(ushort4*)(dst + 4) = make_ushort4(tmp[4], tmp[5], tmp[6], tmp[7]);
}

// ---------- Kernel 1: QKV projection ----------
// grid 512 (M=32 token rows), 256 threads (4 waves). BK=64, 16 k-steps.
// Depth-2 register prefetch of x + v_cvt_pk_bf16_f32 staging conversion.
// Q is pre-scaled by SLOG2E so attn3's softmax needs no per-score mul.
__global__ __launch_bounds__(256) void qkv5(
    const float* __restrict__ x, const unsigned short* __restrict__ WTf,
    unsigned short* __restrict__ Qb, unsigned short* __restrict__ Kb,
    unsigned short* __restrict__ VTt) {
  __shared__ __align__(16) unsigned short Af[2048];   // 4 KB

  int mt = blockIdx.x;
  int t = threadIdx.x;
  int wv = t >> 6, lane = t & 63;
  int lrow = lane & 15, quad = lane >> 4;

  floatx4 acc[2][3];   // [m-sub][n-group]
#pragma unroll
  for (int g2 = 0; g2 < 2; ++g2)
#pragma unroll
    for (int j = 0; j < 3; ++j)
#pragma unroll
      for (int r = 0; r < 4; ++r) acc[g2][j][r] = 0.f;

  // staging coords: thread covers (row srow, k-chunk scg of 8)
  int srow = t >> 3, scg = t & 7;
  int skc2 = scg >> 2, squad = scg & 3;
  int sslot = ((srow >> 4) * 2 + skc2) * 64 + squad * 16 +
              (((srow & 15) + squad + 4 * skc2) & 15);
  const float* xp = x + (size_t)(mt * 32 + srow) * Cc + scg * 8;

  // frag-read slots (swizzled)
  int aslot[2][2];
#pragma unroll
  for (int g2 = 0; g2 < 2; ++g2)
#pragma unroll
    for (int kc2 = 0; kc2 < 2; ++kc2)
      aslot[g2][kc2] = ((g2 * 2 + kc2) * 64 + quad * 16 +
                        ((lrow + quad + 4 * kc2) & 15)) * 8;

  const unsigned short* wbase[3];
#pragma unroll
  for (int j = 0; j < 3; ++j)
    wbase[j] = WTf + (size_t)(wv * 3 + j) * 32 * 512 + lane * 8;

  // depth-2 prefetch registers (two k-steps in flight)
  float4 va0 = *(const float4*)xp;
  float4 va1 = *(const float4*)(xp + 4);
  float4 vb0 = *(const float4*)(xp + 64);
  float4 vb1 = *(const float4*)(xp + 68);

  auto cvt8 = [](const float4& u, const float4& v) -> short8 {
    unsigned int p0, p1, p2, p3;
    asm("v_cvt_pk_bf16_f32 %0, %1, %2" : "=v"(p0) : "v"(u.x), "v"(u.y));
    asm("v_cvt_pk_bf16_f32 %0, %1, %2" : "=v"(p1) : "v"(u.z), "v"(u.w));
    asm("v_cvt_pk_bf16_f32 %0, %1, %2" : "=v"(p2) : "v"(v.x), "v"(v.y));
    asm("v_cvt_pk_bf16_f32 %0, %1, %2" : "=v"(p3) : "v"(v.z), "v"(v.w));
    uint4v w; w[0] = p0; w[1] = p1; w[2] = p2; w[3] = p3;
    return __builtin_bit_cast(short8, w);
  };

  auto step = [&](float4& n0, float4& n1, int kk) {
    __syncthreads();   // prior frag reads done before overwrite
    short8 a = cvt8(n0, n1);
    *(short8*)&Af[sslot * 8] = a;
    if (kk + 2 < 16) {   // prefetch two steps ahead across the compute phase
      n0 = *(const float4*)(xp + (kk + 2) * 64);
      n1 = *(const float4*)(xp + (kk + 2) * 64 + 4);
    }
    __syncthreads();

    short8 bf[3][2];
    int kg = kk * 2;
#pragma unroll
    for (int j = 0; j < 3; ++j)
#pragma unroll
      for (int kc2 = 0; kc2 < 2; ++kc2)
        bf[j][kc2] = *(const short8*)(wbase[j] + (size_t)(kg + kc2) * 512);
    short8 af[2][2];
#pragma unroll
    for (int g2 = 0; g2 < 2; ++g2)
#pragma unroll
      for (int kc2 = 0; kc2 < 2; ++kc2)
        af[g2][kc2] = *(const short8*)&Af[aslot[g2][kc2]];
#pragma unroll
    for (int g2 = 0; g2 < 2; ++g2)
#pragma unroll
      for (int j = 0; j < 3; ++j) {
        acc[g2][j] = __builtin_amdgcn_mfma_f32_16x16x32_bf16(af[g2][0], bf[j][0], acc[g2][j], 0, 0, 0);
        acc[g2][j] = __builtin_amdgcn_mfma_f32_16x16x32_bf16(af[g2][1], bf[j][1], acc[g2][j], 0, 0, 0);
      }
  };

#pragma unroll
  for (int kk2 = 0; kk2 < 8; ++kk2) {
    step(va0, va1, kk2 * 2);
    step(vb0, vb1, kk2 * 2 + 1);
  }

  // epilogue: D row(m)=quad*4+r, col(n)=lrow. Q pre-scaled by SLOG2E.
#pragma unroll
  for (int g2 = 0; g2 < 2; ++g2) {
    int tok0 = mt * 32 + g2 * 16 + quad * 4;
#pragma unroll
    for (int j = 0; j < 3; ++j) {
      int nbase = (wv * 3 + j) * 16;
      if (nbase >= 128) {
        int h = nbase - 128 + lrow;
        // VTt: per-64-token tile, [ktile][h][tok&63], rows 128 B apart
        *(ushort4*)&VTt[(size_t)(tok0 >> 6) * 4096 + h * 64 + (tok0 & 63)] =
            make_ushort4(f2bf(acc[g2][j][0]), f2bf(acc[g2][j][1]),
                         f2bf(acc[g2][j][2]), f2bf(acc[g2][j][3]));
      } else {
        unsigned short* dst = (nbase >= 64) ? Kb : Qb;
        float sc = (nbase >= 64) ? 1.0f : SLOG2E;
        int col = (nbase & 63) + lrow;
#pragma unroll
        for (int r = 0; r < 4; ++r)
          dst[(size_t)(tok0 + r) * Hh + col] = f2bf(acc[g2][j][r] * sc);
      }
    }
  }
}

// ---------- Kernel 2: causal attention, no-max softmax ----------
// grid 256 blocks (b, j), 512 threads (8 waves). Block handles query tiles
// j and 63-j sequentially; key blocks split 8-way across waves; no barriers
// in K-loop. Unnormalized softmax P = exp2(S) (S pre-scaled via Qb).
//
// P path: per (qs,sn) pack 4 q-consecutive P values (v_cvt_pk_bf16_f32 x2)
// and ds_write_b64 into slot layout S(q,k32) = (k32>>2)*64 + (k32&3)*16 + q
// (elements, within the (qs,kc=sn>>1) 512-elem slot).
// Read back as A-frags via ds_read_b64_tr_b16:
//   per-lane byte addr = slot + quad*256 + lrow*8  -> elems quad*128+lrow+16j
//   = A[row=lrow][k32=quad*8+j]; offset:128 gives k32=quad*8+4+j.
// (tr-read column granularity is 8 BYTES within each 128-byte block; the
//  round-1 failure was stepping the column by 2 bytes + a 512-byte imm.)
__global__ __launch_bounds__(512) void attn3(
    const unsigned short* __restrict__ Qb, const unsigned short* __restrict__ Kb,
    const unsigned short* __restrict__ VTt, float* __restrict__ out) {
  __shared__ __align__(16) unsigned char smem[33 * 1024];
  unsigned short* Pall = (unsigned short*)smem;
  unsigned short* Ocomb = (unsigned short*)smem;
  float* Lcomb = (float*)(smem + 32768);

  int bid = blockIdx.x;
  int b = bid >> 5;
  int j = bid & 31;
  int t = threadIdx.x;
  int wv = t >> 6, lane = t & 63;
  int lrow = lane & 15, quad = lane >> 4;

  unsigned short* Pw = Pall + wv * 2048;
  unsigned int pbase = (unsigned int)(size_t)Pw;   // low 32 bits = LDS byte offset

  // loop-invariant tr-read base addresses (bytes); k32=quad*8+4+j at +128
  unsigned int paddr[2][2];
#pragma unroll
  for (int qs = 0; qs < 2; ++qs)
#pragma unroll
    for (int kc = 0; kc < 2; ++kc)
      paddr[qs][kc] = pbase + (unsigned int)(qs * 2048 + kc * 1024 + quad * 256 + lrow * 8);

  // loop-invariant part of the P^T write offset (ushort elements)
  int wbase_off = (lrow >> 2) * 64 + (lrow & 3) * 16 + quad * 4;

  short8 ones;
#pragma unroll
  for (int i = 0; i < 8; ++i) ones[i] = (short)0x3F80;

  for (int half = 0; half < 2; ++half) {
    int qt = half ? (63 - j) : j;
    int q0 = qt * 32;
    int nkt = (qt >> 1) + 1;

    short8 aq[2][2];
#pragma unroll
    for (int qs = 0; qs < 2; ++qs)
#pragma unroll
      for (int kc = 0; kc < 2; ++kc)
        aq[qs][kc] = *(const short8*)
            &Qb[(size_t)(b * Tt + q0 + qs * 16 + lrow) * Hh + kc * 32 + quad * 8];

    floatx4 acc_o[2][4];
    floatx4 acc_l[2];
#pragma unroll
    for (int qs = 0; qs < 2; ++qs) {
#pragma unroll
      for (int r = 0; r < 4; ++r) acc_l[qs][r] = 0.f;
#pragma unroll
      for (int hs = 0; hs < 4; ++hs)
#pragma unroll
        for (int r = 0; r < 4; ++r) acc_o[qs][hs][r] = 0.f;
    }

    for (int kt = wv; kt < nkt; kt += 8) {
      int kbase = b * Tt + kt * 64;
      short8 kf[4][2], vf[4][2];
#pragma unroll
      for (int sn = 0; sn < 4; ++sn)
#pragma unroll
        for (int kc = 0; kc < 2; ++kc)
          kf[sn][kc] = *(const short8*)
              &Kb[(size_t)(kbase + sn * 16 + lrow) * Hh + kc * 32 + quad * 8];
      int ktile = b * 32 + kt;
#pragma unroll
      for (int hs = 0; hs < 4; ++hs)
#pragma unroll
        for (int kc = 0; kc < 2; ++kc)
          vf[hs][kc] = *(const short8*)
              &VTt[(size_t)ktile * 4096 + (hs * 16 + lrow) * 64 + kc * 32 + quad * 8];

      floatx4 s[2][4];
      __builtin_amdgcn_s_setprio(1);
#pragma unroll
      for (int qs = 0; qs < 2; ++qs)
#pragma unroll
        for (int sn = 0; sn < 4; ++sn) {
          floatx4 z;
#pragma unroll
          for (int r = 0; r < 4; ++r) z[r] = 0.f;
          z = __builtin_amdgcn_mfma_f32_16x16x32_bf16(aq[qs][0], kf[sn][0], z, 0, 0, 0);
          z = __builtin_amdgcn_mfma_f32_16x16x32_bf16(aq[qs][1], kf[sn][1], z, 0, 0, 0);
          s[qs][sn] = z;
        }
      __builtin_amdgcn_s_setprio(0);

      bool diag = (kt == nkt - 1);
#pragma unroll
      for (int qs = 0; qs < 2; ++qs)
#pragma unroll
        for (int sn = 0; sn < 4; ++sn) {
          float p[4];
#pragma unroll
          for (int r = 0; r < 4; ++r) {
            float v = s[qs][sn][r];   // already scaled (Q pre-scaled)
            if (diag) {
              int gk = kt * 64 + sn * 16 + lrow;
              int gq = q0 + qs * 16 + quad * 4 + r;
              if (gk > gq) v = -INFINITY;
            }
            p[r] = __builtin_amdgcn_exp2f(v);   // exp2(-inf)=0
          }
          unsigned int w0, w1;
          asm("v_cvt_pk_bf16_f32 %0, %1, %2" : "=v"(w0) : "v"(p[0]), "v"(p[1]));
          asm("v_cvt_pk_bf16_f32 %0, %1, %2" : "=v"(w1) : "v"(p[2]), "v"(p[3]));
          int woff = qs * 1024 + (sn >> 1) * 512 + (sn & 1) * 256 + wbase_off;
          *(uint2*)&Pw[woff] = make_uint2(w0, w1);
        }

      // drain the b64 writes, then transpose-read A-fragments
      asm volatile("s_waitcnt lgkmcnt(0)" ::: "memory");
      short8 ap[2][2];
#pragma unroll
      for (int qs = 0; qs < 2; ++qs)
#pragma unroll
        for (int kc = 0; kc < 2; ++kc) {
          s16x4 lo, hi;
          asm volatile("ds_read_b64_tr_b16 %0, %1"
                       : "=v"(lo) : "v"(paddr[qs][kc]) : "memory");
          asm volatile("ds_read_b64_tr_b16 %0, %1 offset:128"
                       : "=v"(hi) : "v"(paddr[qs][kc]) : "memory");
          ap[qs][kc] = __builtin_shufflevector(lo, hi, 0, 1, 2, 3, 4, 5, 6, 7);
        }
      asm volatile("s_waitcnt lgkmcnt(0)" ::: "memory");
      __builtin_amdgcn_sched_barrier(0);

      __builtin_amdgcn_s_setprio(1);
#pragma unroll
      for (int qs = 0; qs < 2; ++qs) {
        acc_l[qs] = __builtin_amdgcn_mfma_f32_16x16x32_bf16(ap[qs][0], ones, acc_l[qs], 0, 0, 0);
        acc_l[qs] = __builtin_amdgcn_mfma_f32_16x16x32_bf16(ap[qs][1], ones, acc_l[qs], 0, 0, 0);
#pragma unroll
        for (int hs = 0; hs < 4; ++hs) {
          acc_o[qs][hs] = __builtin_amdgcn_mfma_f32_16x16x32_bf16(ap[qs][0], vf[hs][0], acc_o[qs][hs], 0, 0, 0);
          acc_o[qs][hs] = __builtin_amdgcn_mfma_f32_16x16x32_bf16(ap[qs][1], vf[hs][1], acc_o[qs][hs], 0, 0, 0);
        }
      }
      __builtin_amdgcn_s_setprio(0);
    }

    // ---- combine partials ----
#pragma unroll
    for (int qs = 0; qs < 2; ++qs)
#pragma unroll
      for (int hs = 0; hs < 4; ++hs) {
        int s8 = qs * 4 + hs;
        *(ushort4*)&Ocomb[((wv * 8 + s8) * 64 + lane) * 4] =
            make_ushort4(f2bf(acc_o[qs][hs][0]), f2bf(acc_o[qs][hs][1]),
                         f2bf(acc_o[qs][hs][2]), f2bf(acc_o[qs][hs][3]));
      }
    if (lrow == 0) {
#pragma unroll
      for (int qs = 0; qs < 2; ++qs)
#pragma unroll
        for (int r = 0; r < 4; ++r)
          Lcomb[wv * 32 + qs * 16 + quad * 4 + r] = acc_l[qs][r];
    }
    __syncthreads();

    {
      int qsub = wv >> 2, hs = wv & 3;
      float o[4] = {0.f, 0.f, 0.f, 0.f};
#pragma unroll
      for (int w = 0; w < 8; ++w) {
        ushort4 pk = *(const ushort4*)&Ocomb[((w * 8 + wv) * 64 + lane) * 4];
        o[0] += bf2f(pk.x); o[1] += bf2f(pk.y);
        o[2] += bf2f(pk.z); o[3] += bf2f(pk.w);
      }
#pragma unroll
      for (int r = 0; r < 4; ++r) {
        float lv = 0.f;
#pragma unroll
        for (int w = 0; w < 8; ++w)
          lv += Lcomb[w * 32 + qsub * 16 + quad * 4 + r];
        int row = q0 + qsub * 16 + quad * 4 + r;
        out[(size_t)(b * Tt + row) * Hh + hs * 16 + lrow] = o[r] / lv;
      }
    }
    __syncthreads();
  }
}

extern "C" void kernel_launch(void* const* d_in, const int* in_sizes, int n_in,
                              void* d_out, int out_size, void* d_ws, size_t ws_size,
                              hipStream_t stream) {
  const float* x = (const float*)d_in[0];
  const float* Wq = (const float*)d_in[1];
  const float* Wk = (const float*)d_in[2];
  const float* Wv = (const float*)d_in[3];
  float* out = (float*)d_out;

  unsigned short* WTf = (unsigned short*)d_ws;         // 192*1024 frag-major
  unsigned short* Qb = WTf + 192 * 1024;               // [BT][64]
  unsigned short* Kb = Qb + (size_t)BT * Hh;           // [BT][64]
  unsigned short* VTt = Kb + (size_t)BT * Hh;          // [BT/64][64][64]

  wconv2<<<dim3(96), dim3(256), 0, stream>>>(Wq, Wk, Wv, WTf);
  qkv5<<<dim3(512), dim3(256), 0, stream>>>(x, WTf, Qb, Kb, VTt);
  attn3<<<dim3(256), dim3(512), 0, stream>>>(Qb, Kb, VTt, out);
}